// Round 7
// baseline (140.258 us; speedup 1.0000x reference)
//
#include <hip/hip_runtime.h>
#include <hip/hip_bf16.h>
#include <hip/hip_fp16.h>
#include <cstdint>

#define IND 128
#define HID 64
#define NEG_SLOPE 0.2f
#define EPB 4096      // edges per sort block
#define CBSHIFT 6     // bucket = 64 consecutive dst nodes (round-21: was 8)
#define BCAP 2048     // per-bucket capacity (mean 1088, +29 sigma)
#define NBH 784       // histogram slots (782 buckets, padded)
#define SORT_THREADS 256
#define EPT (EPB / SORT_THREADS)   // 16 edges per thread in sort role
#define GT 512        // gather-block threads
#define GSCAN (BCAP / GT)          // 4: scan iters per gather block

typedef __attribute__((ext_vector_type(8))) short bf16x8;
typedef __attribute__((ext_vector_type(4))) float f32x4;

__device__ __forceinline__ unsigned short f2bf_bits(float f) {
  __hip_bfloat16 b = __float2bfloat16(f);
  return *reinterpret_cast<unsigned short*>(&b);
}
__device__ __forceinline__ unsigned short f2h_bits(float f) {
  __half h = __float2half(f);
  return *reinterpret_cast<unsigned short*>(&h);
}
__device__ __forceinline__ float h2f_bits(unsigned short u) {
  __half_raw r; r.x = u;
  return __half2float(__half(r));
}
__device__ __forceinline__ float bf2f_bits(unsigned short u) {
  return __uint_as_float((unsigned)u << 16);
}
__device__ __forceinline__ unsigned pack_bf2(float lo, float hi) {
  return (unsigned)f2bf_bits(lo) | ((unsigned)f2bf_bits(hi) << 16);
}
__device__ __forceinline__ bf16x8 mk_bf16x8(unsigned a, unsigned b,
                                            unsigned c, unsigned d) {
  union { unsigned u[4]; bf16x8 v; } t;
  t.u[0] = a; t.u[1] = b; t.u[2] = c; t.u[3] = d;
  return t.v;
}
__device__ __forceinline__ bf16x8 mk_bf16x8_u4(uint4 u) {
  union { uint4 u4; bf16x8 v; } t;
  t.u4 = u;
  return t.v;
}

// ---------------------------------------------------------------------------
// K1 (fused): proj + sortout in one grid, block-role split.
//   blocks [0, nSort)        : counting-sort role -> 64-NODE buckets (r21)
//   blocks [nSort, nSort+nP) : projection role — MFMA (round-20 proven)
// Round-6 post-mortem: csr_gather's scan/fill paid 4x duplicated reads +
// dl<64 filtering because sort buckets (256 nodes) were coarser than
// gather blocks (64 nodes). Fix: sort histograms 782 fine buckets.
// Thread t owns buckets 4t..4t+3 (serial 4-scan) + the existing 256-wide
// block scan over per-thread totals. Scatter/write-out mechanics
// unchanged; write-out slot-clamped so a capacity-analysis error degrades
// (drops an edge) instead of faulting.
// LDS sort role: 4x784 + 256 ints (13.5 KB) + sorted 16 KB = 29.9 KB.
// gcur zeroed by a tiny hipMemsetAsync before launch.
// ---------------------------------------------------------------------------
__global__ __launch_bounds__(256) void k_proj_sort(
    const float* __restrict__ x, const float* __restrict__ W,
    const float* __restrict__ att_s, const float* __restrict__ att_d,
    unsigned short* __restrict__ h, float* __restrict__ a_src,
    float* __restrict__ a_dst,
    const int* __restrict__ ei, int* __restrict__ gcur,
    unsigned* __restrict__ tmp, int E, long long E2,
    int nSort, int nbuck, int n)
{
  __shared__ __align__(16) char smem[29952];
  const int tid = threadIdx.x;

  if (blockIdx.x < (unsigned)nSort) {
    // ---------------- sort role ----------------
    int* hist  = (int*)smem;             // NBH counts
    int* locs  = hist + NBH;             // NBH local (in-block) run starts
    int* gbase = locs + NBH;             // NBH reserved global run bases
    int* cur   = gbase + NBH;            // NBH scatter cursors
    int* tsum  = cur + NBH;              // 256 per-thread totals (scan)
    unsigned* sorted = (unsigned*)(tsum + 256);   // EPB entries (16 KB)

    for (int i = tid; i < NBH; i += SORT_THREADS) hist[i] = 0;
    __syncthreads();

    const long long i0 = (long long)blockIdx.x * EPB;

    unsigned pk[EPT];
#pragma unroll
    for (int j = 0; j < EPT; ++j) {
      long long idx = i0 + j * SORT_THREADS + tid;
      unsigned v = 0xFFFFFFFFu;
      if (idx < E2) {
        int s, d;
        if (idx < E) { s = ei[idx]; d = ei[E + idx]; }
        else         { s = d = (int)(idx - E); }
        v = ((unsigned)d << 16) | (unsigned)s;
        atomicAdd(&hist[d >> CBSHIFT], 1);
      }
      pk[j] = v;
    }
    __syncthreads();

    // per-thread serial scan over 4 owned buckets, then 256-wide scan
    int t1 = 0, t2 = 0, t3 = 0, tot = 0;
    const int b0 = tid * 4;
    if (b0 < NBH) {
      t1 = hist[b0];
      t2 = t1 + hist[b0 + 1];
      t3 = t2 + hist[b0 + 2];
      tot = t3 + hist[b0 + 3];
    }
    tsum[tid] = tot;
    __syncthreads();
    for (int off = 1; off < 256; off <<= 1) {
      int t = (tid >= off) ? tsum[tid - off] : 0;
      __syncthreads();
      tsum[tid] += t;
      __syncthreads();
    }
    if (b0 < NBH) {
      const int ex = tsum[tid] - tot;      // exclusive start of thread's span
      locs[b0]     = ex;
      locs[b0 + 1] = ex + t1;
      locs[b0 + 2] = ex + t2;
      locs[b0 + 3] = ex + t3;
#pragma unroll
      for (int k = 0; k < 4; ++k) {
        const int b = b0 + k;
        const int c = hist[b];
        gbase[b] = (b < nbuck && c > 0)
                     ? b * BCAP + atomicAdd(&gcur[b], c) : 0;
        cur[b] = locs[b];
      }
    }
    __syncthreads();

#pragma unroll
    for (int j = 0; j < EPT; ++j) {
      unsigned v = pk[j];
      if (v != 0xFFFFFFFFu) {
        int b = v >> (16 + CBSHIFT);
        int lpos = atomicAdd(&cur[b], 1);
        sorted[lpos] = v;
      }
    }
    __syncthreads();

    const int cntE = (int)((E2 - i0 < EPB) ? (E2 - i0) : EPB);
    for (int i = tid; i < cntE; i += SORT_THREADS) {
      unsigned v = sorted[i];
      int b = v >> (16 + CBSHIFT);
      int slot = gbase[b] + (i - locs[b]);
      if (slot < (b + 1) * BCAP) tmp[slot] = v;   // overflow guard
    }
    return;
  }

  // ---------------- proj role (MFMA, round-20 proven) ----------------
  unsigned* wt = (unsigned*)smem;       // 64 rows x 16 uint4 bf16x2, swizzled

  const int nodeBase = (blockIdx.x - nSort) * 64;

  // stage W -> bf16 LDS (identical layout + swizzle to round-15)
#pragma unroll
  for (int it = 0; it < 4; ++it) {
    int fi = (it * 256 + tid) * 8;        // flat float idx (8192 total)
    int row = fi >> 7, k = fi & 127;
    float4 w0 = *(const float4*)(W + fi);
    float4 w1 = *(const float4*)(W + fi + 4);
    uint4 pv;
    pv.x = pack_bf2(w0.x, w0.y);
    pv.y = pack_bf2(w0.z, w0.w);
    pv.z = pack_bf2(w1.x, w1.y);
    pv.w = pack_bf2(w1.z, w1.w);
    int c = (k >> 3) ^ ((row >> 2) & 7);  // 16B-chunk swizzle
    ((uint4*)wt)[row * 16 + c] = pv;
  }
  __syncthreads();

  const int lane = tid & 63;
  const int wid4 = tid >> 6;            // wave 0..3: H rows [16*wid4, +16)
  const int r16  = lane & 15;           // A row in stripe / B+D col in tile
  const int q    = lane >> 4;           // k-subgroup (8 bf16 each)

  const int arow = nodeBase + 16 * wid4 + r16;
  const size_t xoff = (size_t)((arow < n) ? arow : (n - 1)) * IND;

  // issue all 8 x-loads up front (independent; hide HBM latency)
  float4 xv[8];
#pragma unroll
  for (int ks = 0; ks < 4; ++ks) {
    xv[2 * ks]     = *(const float4*)(x + xoff + 32 * ks + 8 * q);
    xv[2 * ks + 1] = *(const float4*)(x + xoff + 32 * ks + 8 * q + 4);
  }

  f32x4 acc0 = {0.f, 0.f, 0.f, 0.f};
  f32x4 acc1 = {0.f, 0.f, 0.f, 0.f};
  f32x4 acc2 = {0.f, 0.f, 0.f, 0.f};
  f32x4 acc3 = {0.f, 0.f, 0.f, 0.f};

#pragma unroll
  for (int ks = 0; ks < 4; ++ks) {      // K-step: k0 = 32*ks
    float4 xa = xv[2 * ks], xb = xv[2 * ks + 1];
    bf16x8 afrag = mk_bf16x8(pack_bf2(xa.x, xa.y), pack_bf2(xa.z, xa.w),
                             pack_bf2(xb.x, xb.y), pack_bf2(xb.z, xb.w));
    // B chunk index = (k0>>3)+q = 4*ks+q, XOR row-swizzled
    {
      int row = r16;                    // col-tile 0
      uint4 bw = ((const uint4*)wt)[row * 16 + ((4 * ks + q) ^ ((row >> 2) & 7))];
      acc0 = __builtin_amdgcn_mfma_f32_16x16x32_bf16(afrag, mk_bf16x8_u4(bw), acc0, 0, 0, 0);
    }
    {
      int row = 16 + r16;               // col-tile 1
      uint4 bw = ((const uint4*)wt)[row * 16 + ((4 * ks + q) ^ ((row >> 2) & 7))];
      acc1 = __builtin_amdgcn_mfma_f32_16x16x32_bf16(afrag, mk_bf16x8_u4(bw), acc1, 0, 0, 0);
    }
    {
      int row = 32 + r16;               // col-tile 2
      uint4 bw = ((const uint4*)wt)[row * 16 + ((4 * ks + q) ^ ((row >> 2) & 7))];
      acc2 = __builtin_amdgcn_mfma_f32_16x16x32_bf16(afrag, mk_bf16x8_u4(bw), acc2, 0, 0, 0);
    }
    {
      int row = 48 + r16;               // col-tile 3
      uint4 bw = ((const uint4*)wt)[row * 16 + ((4 * ks + q) ^ ((row >> 2) & 7))];
      acc3 = __builtin_amdgcn_mfma_f32_16x16x32_bf16(afrag, mk_bf16x8_u4(bw), acc3, 0, 0, 0);
    }
  }

  // epilogue: D row = 4*q + reg (within stripe), col = t*16 + r16
  const float as0 = att_s[r16],      ad0 = att_d[r16];
  const float as1 = att_s[16 + r16], ad1 = att_d[16 + r16];
  const float as2 = att_s[32 + r16], ad2 = att_d[32 + r16];
  const float as3 = att_s[48 + r16], ad3 = att_d[48 + r16];

#pragma unroll
  for (int reg = 0; reg < 4; ++reg) {
    const int node = nodeBase + 16 * wid4 + 4 * q + reg;
    const bool ok = (node < n);
    if (ok) {
      const size_t hb = (size_t)node * HID;
      h[hb + r16]      = f2bf_bits(acc0[reg]);
      h[hb + 16 + r16] = f2bf_bits(acc1[reg]);
      h[hb + 32 + r16] = f2bf_bits(acc2[reg]);
      h[hb + 48 + r16] = f2bf_bits(acc3[reg]);
    }
    float ps = acc0[reg] * as0 + acc1[reg] * as1 + acc2[reg] * as2 + acc3[reg] * as3;
    float pd = acc0[reg] * ad0 + acc1[reg] * ad1 + acc2[reg] * ad2 + acc3[reg] * ad3;
    ps += __shfl_xor(ps, 1, 64); ps += __shfl_xor(ps, 2, 64);
    ps += __shfl_xor(ps, 4, 64); ps += __shfl_xor(ps, 8, 64);
    pd += __shfl_xor(pd, 1, 64); pd += __shfl_xor(pd, 2, 64);
    pd += __shfl_xor(pd, 4, 64); pd += __shfl_xor(pd, 8, 64);
    if (ok && r16 == 0) { a_src[node] = ps; a_dst[node] = pd; }
  }
}

// ---------------------------------------------------------------------------
// K2 (round-21): per-64-node-bucket CSR build + gather + epilogue.
// Sort now delivers exact per-bucket runs -> each block reads ONLY its own
// ~1088-entry run (was: 4x duplicated coarse-bucket scan + dl<64 filter).
// pkv cache shrinks 16 -> 4 regs. Gather body = round-12 proven wave
// kernel, unchanged. 782 blocks x 512 thr, 4 blocks/CU (thread-limited).
// ---------------------------------------------------------------------------
__global__ __launch_bounds__(GT) void k_csr_gather(
    const unsigned* __restrict__ tmp, const int* __restrict__ gcur,
    const float* __restrict__ a_src, const float* __restrict__ a_dst,
    const unsigned short* __restrict__ h,
    const float* __restrict__ bias, const float* __restrict__ W_lin,
    const float* __restrict__ b_lin, float* __restrict__ y, int n)
{
  __shared__ int degl[64], sums[64], cur[64];
  __shared__ float adl[64];
  __shared__ unsigned csrw[BCAP];          // bucket CSR: (src | w_fp16<<16)

  const int tid  = threadIdx.x;
  const int b    = blockIdx.x;
  const int n0   = b << CBSHIFT;
  const int base = b * BCAP;
  int run = gcur[b]; if (run > BCAP) run = BCAP;   // clamp (guard pair)
  const int next = base + run;

  if (tid < 64) {
    degl[tid] = 0;
    const int node = n0 + tid;
    adl[tid] = (node < n) ? a_dst[node] : 0.f;
  }
  __syncthreads();

  // single scan of our own run, cached in registers
  unsigned pkv[GSCAN];
#pragma unroll
  for (int j = 0; j < GSCAN; ++j) {
    int i = base + j * GT + tid;
    unsigned v = 0xFFFFFFFFu;
    if (i < next) {
      v = tmp[i];
      unsigned dl = (v >> 16) - (unsigned)n0;
      if (dl < 64u) atomicAdd(&degl[dl], 1);
      else v = 0xFFFFFFFFu;                // corrupt-entry guard (never fires)
    }
    pkv[j] = v;
  }
  __syncthreads();

  if (tid < 64) sums[tid] = degl[tid];
  __syncthreads();
  for (int off = 1; off < 64; off <<= 1) {
    int t = (tid >= off && tid < 64) ? sums[tid - off] : 0;
    __syncthreads();
    if (tid < 64) sums[tid] += t;
    __syncthreads();
  }
  if (tid < 64) cur[tid] = sums[tid] - degl[tid];   // bucket-local row start
  __syncthreads();

#pragma unroll
  for (int j = 0; j < GSCAN; ++j) {
    unsigned v = pkv[j];
    if (v != 0xFFFFFFFFu) {
      unsigned dl = (v >> 16) - (unsigned)n0;
      int s = (int)(v & 0xFFFFu);
      float sc = a_src[s] + adl[dl];
      sc = (sc >= 0.f) ? sc : NEG_SLOPE * sc;
      float w = expf(sc);
      int pos = atomicAdd(&cur[dl], 1);
      if (pos < BCAP)                       // structural bound; cheap safety
        csrw[pos] = (unsigned)s | ((unsigned)f2h_bits(w) << 16);
    }
  }
  __syncthreads();

  // -------- gather + epilogue (round-12 proven wave body, LDS weights) ----
  const int lane    = tid & 63;
  const int wid     = tid >> 6;            // 8 waves
  const int quarter = lane >> 4;           // which edge of the 4-group
  const int sub     = lane & 15;           // dim quad: dims 4sub .. 4sub+3

  for (int nl = wid; nl < 64; nl += 8) {
    const int node = n0 + nl;
    if (node >= n) break;                  // nl increasing; wave-uniform

    int rsl = sums[nl] - degl[nl];         // LDS-local row start
    int dg  = degl[nl];
    if (rsl + dg > BCAP) dg = (BCAP > rsl) ? (BCAP - rsl) : 0;  // guard pair
    if (rsl >= BCAP) { rsl = 0; dg = 0; }

    float wpart = 0.f;
    float acc0 = 0.f, acc1 = 0.f, acc2 = 0.f, acc3 = 0.f;

    for (int bb = 0; bb < dg; bb += 64) {
      int i = bb + lane;
      unsigned pk = (i < dg) ? csrw[rsl + i] : 0u;   // w bits 0 -> w = 0
      wpart += h2f_bits((unsigned short)(pk >> 16));
      const int cnt = (dg - bb < 64) ? (dg - bb) : 64;

      int j = 0;
      for (; j + 8 <= cnt; j += 8) {
#pragma unroll
        for (int g = 0; g < 2; ++g) {
          int e = j + 4 * g + quarter;
          unsigned pe = __shfl(pk, e, 64);
          float we = h2f_bits((unsigned short)(pe >> 16));
          unsigned se = pe & 0xFFFFu;
          ushort4 hb = ((const ushort4*)(h + (size_t)se * HID))[sub];
          acc0 = fmaf(we, bf2f_bits(hb.x), acc0);
          acc1 = fmaf(we, bf2f_bits(hb.y), acc1);
          acc2 = fmaf(we, bf2f_bits(hb.z), acc2);
          acc3 = fmaf(we, bf2f_bits(hb.w), acc3);
        }
      }
      for (; j < cnt; j += 4) {
        int e = j + quarter;
        bool val = e < cnt;
        unsigned pe = __shfl(pk, val ? e : 0, 64);
        float we = val ? h2f_bits((unsigned short)(pe >> 16)) : 0.f;
        unsigned se = val ? (pe & 0xFFFFu) : 0u;
        ushort4 hb = ((const ushort4*)(h + (size_t)se * HID))[sub];
        acc0 = fmaf(we, bf2f_bits(hb.x), acc0);
        acc1 = fmaf(we, bf2f_bits(hb.y), acc1);
        acc2 = fmaf(we, bf2f_bits(hb.z), acc2);
        acc3 = fmaf(we, bf2f_bits(hb.w), acc3);
      }
    }

    acc0 += __shfl_xor(acc0, 16, 64); acc0 += __shfl_xor(acc0, 32, 64);
    acc1 += __shfl_xor(acc1, 16, 64); acc1 += __shfl_xor(acc1, 32, 64);
    acc2 += __shfl_xor(acc2, 16, 64); acc2 += __shfl_xor(acc2, 32, 64);
    acc3 += __shfl_xor(acc3, 16, 64); acc3 += __shfl_xor(acc3, 32, 64);

    float wsum = wpart;
#pragma unroll
    for (int o = 32; o; o >>= 1) wsum += __shfl_xor(wsum, o, 64);
    const float inv = 1.f / wsum;

    float4 bb4 = ((const float4*)bias)[sub];
    float4 ww  = ((const float4*)W_lin)[sub];
    float v0 = fmaxf(acc0 * inv + bb4.x, 0.f);
    float v1 = fmaxf(acc1 * inv + bb4.y, 0.f);
    float v2 = fmaxf(acc2 * inv + bb4.z, 0.f);
    float v3 = fmaxf(acc3 * inv + bb4.w, 0.f);
    float z = v0 * ww.x + v1 * ww.y + v2 * ww.z + v3 * ww.w;
#pragma unroll
    for (int o = 8; o; o >>= 1) z += __shfl_xor(z, o, 64);
    if (lane == 0)
      y[node] = 1.f / (1.f + expf(-(z + b_lin[0])));
  }
}

// ---------------------------------------------------------------------------

extern "C" void kernel_launch(void* const* d_in, const int* in_sizes, int n_in,
                              void* d_out, int out_size, void* d_ws, size_t ws_size,
                              hipStream_t stream)
{
  const float* x     = (const float*)d_in[0];
  const int*   ei    = (const int*)d_in[1];
  const float* W     = (const float*)d_in[2];
  const float* att_s = (const float*)d_in[3];
  const float* att_d = (const float*)d_in[4];
  const float* bias  = (const float*)d_in[5];
  const float* W_lin = (const float*)d_in[6];
  const float* b_lin = (const float*)d_in[7];
  float* y = (float*)d_out;

  const int n = in_sizes[0] / IND;
  const int E = in_sizes[1] / 2;
  const long long E2 = (long long)E + n;
  const int nSort = (int)((E2 + EPB - 1) / EPB);         // sort blocks (208)
  const int nProj = (n + 63) / 64;                       // proj blocks (782)
  const int nbuck = (n + (1 << CBSHIFT) - 1) >> CBSHIFT; // fine buckets (782)

  // Workspace (~13 MB). gcur zeroed by the async memset below; everything
  // else fully written before read, every call.
  char* ws = (char*)d_ws;
  unsigned short* h = (unsigned short*)ws; ws += (size_t)n * HID * sizeof(unsigned short);
  float*    a_src  = (float*)ws;    ws += (size_t)n * sizeof(float);
  float*    a_dst  = (float*)ws;    ws += (size_t)n * sizeof(float);
  int*      gcur   = (int*)ws;      ws += (size_t)nbuck * sizeof(int);
  unsigned* tmp    = (unsigned*)ws; ws += (size_t)nbuck * BCAP * sizeof(unsigned);

  hipMemsetAsync(gcur, 0, (size_t)nbuck * sizeof(int), stream);

  k_proj_sort<<<nSort + nProj, 256, 0, stream>>>(
      x, W, att_s, att_d, h, a_src, a_dst,
      ei, gcur, tmp, E, E2, nSort, nbuck, n);

  k_csr_gather<<<nbuck, GT, 0, stream>>>(
      tmp, gcur, a_src, a_dst, h, bias, W_lin, b_lin, y, n);
}

// Round 8
// 122.702 us; speedup vs baseline: 1.1431x; 1.1431x over previous
//
#include <hip/hip_runtime.h>
#include <hip/hip_bf16.h>
#include <hip/hip_fp16.h>
#include <cstdint>

#define IND 128
#define HID 64
#define NEG_SLOPE 0.2f
#define EPB 4096      // edges per sort block
#define CBSHIFT 8     // coarse bucket = 256 consecutive dst nodes (r22: reverted)
#define BCAP 8192     // fixed bucket capacity (mean 4352, +60 sigma headroom)
#define SORT_THREADS 256
#define EPT (EPB / SORT_THREADS)   // 16 edges per thread in sort role
#define QCAP 2048     // quarter-bucket CSR capacity (mean 1088, +29 sigma)
#define GT 512        // gather-block threads
#define GSCAN (BCAP / GT)          // 16: max scan iters per gather block

typedef __attribute__((ext_vector_type(8))) short bf16x8;
typedef __attribute__((ext_vector_type(4))) float f32x4;

__device__ __forceinline__ unsigned short f2bf_bits(float f) {
  __hip_bfloat16 b = __float2bfloat16(f);
  return *reinterpret_cast<unsigned short*>(&b);
}
__device__ __forceinline__ unsigned short f2h_bits(float f) {
  __half h = __float2half(f);
  return *reinterpret_cast<unsigned short*>(&h);
}
__device__ __forceinline__ float h2f_bits(unsigned short u) {
  __half_raw r; r.x = u;
  return __half2float(__half(r));
}
__device__ __forceinline__ float bf2f_bits(unsigned short u) {
  return __uint_as_float((unsigned)u << 16);
}
__device__ __forceinline__ unsigned pack_bf2(float lo, float hi) {
  return (unsigned)f2bf_bits(lo) | ((unsigned)f2bf_bits(hi) << 16);
}
__device__ __forceinline__ bf16x8 mk_bf16x8(unsigned a, unsigned b,
                                            unsigned c, unsigned d) {
  union { unsigned u[4]; bf16x8 v; } t;
  t.u[0] = a; t.u[1] = b; t.u[2] = c; t.u[3] = d;
  return t.v;
}
__device__ __forceinline__ bf16x8 mk_bf16x8_u4(uint4 u) {
  union { uint4 u4; bf16x8 v; } t;
  t.u4 = u;
  return t.v;
}

// ---------------------------------------------------------------------------
// K1 (fused): proj + sortout in one grid, block-role split.
//   blocks [0, nSort)        : counting-sort role (round-16 proven, 256 bkts)
//   blocks [nSort, nSort+nP) : projection role — MFMA (round-20 proven)
// Round-7 post-mortem: fine-bucket sort regressed +10 us (5-entry scatter
// segments wasting write lines, 4x gcur atomics, AND smem 29.9 KB cutting
// proj occupancy 8->5 blocks/CU). Reverted to the round-6 form verbatim.
// gcur zeroed by a tiny hipMemsetAsync before launch.
// ---------------------------------------------------------------------------
__global__ __launch_bounds__(256) void k_proj_sort(
    const float* __restrict__ x, const float* __restrict__ W,
    const float* __restrict__ att_s, const float* __restrict__ att_d,
    unsigned short* __restrict__ h, float* __restrict__ a_src,
    float* __restrict__ a_dst,
    const int* __restrict__ ei, int* __restrict__ gcur,
    unsigned* __restrict__ tmp, int E, long long E2,
    int nSort, int nbuck, int n)
{
  __shared__ __align__(16) char smem[20480];
  const int tid = threadIdx.x;

  if (blockIdx.x < (unsigned)nSort) {
    // ---------------- sort role ----------------
    int* hist       = (int*)smem;            // 256 ints: counts, then lstart
    int* sums       = hist + 256;
    int* cur        = sums + 256;
    int* gbase      = cur + 256;             // reserved global run base
    unsigned* sorted = (unsigned*)(gbase + 256);   // EPB entries (16 KB)

    hist[tid] = 0;
    __syncthreads();

    const long long i0 = (long long)blockIdx.x * EPB;

    unsigned pk[EPT];
#pragma unroll
    for (int j = 0; j < EPT; ++j) {
      long long idx = i0 + j * SORT_THREADS + tid;
      unsigned v = 0xFFFFFFFFu;
      if (idx < E2) {
        int s, d;
        if (idx < E) { s = ei[idx]; d = ei[E + idx]; }
        else         { s = d = (int)(idx - E); }
        v = ((unsigned)d << 16) | (unsigned)s;
        atomicAdd(&hist[d >> CBSHIFT], 1);
      }
      pk[j] = v;
    }
    __syncthreads();

    sums[tid] = hist[tid];
    __syncthreads();
    for (int off = 1; off < 256; off <<= 1) {
      int t = (tid >= off) ? sums[tid - off] : 0;
      __syncthreads();
      sums[tid] += t;
      __syncthreads();
    }
    {
      const int lstart_t = sums[tid] - hist[tid];
      cur[tid] = lstart_t;
      gbase[tid] = (tid < nbuck && hist[tid] > 0)
                     ? tid * BCAP + atomicAdd(&gcur[tid], hist[tid]) : 0;
    }
    __syncthreads();
    hist[tid] = sums[tid] - hist[tid];   // hist := lstart
    __syncthreads();

#pragma unroll
    for (int j = 0; j < EPT; ++j) {
      unsigned v = pk[j];
      if (v != 0xFFFFFFFFu) {
        int b = v >> (16 + CBSHIFT);
        int lpos = atomicAdd(&cur[b], 1);
        sorted[lpos] = v;
      }
    }
    __syncthreads();

    const int cntE = (int)((E2 - i0 < EPB) ? (E2 - i0) : EPB);
    for (int i = tid; i < cntE; i += SORT_THREADS) {
      unsigned v = sorted[i];
      int b = v >> (16 + CBSHIFT);
      tmp[gbase[b] + (i - hist[b])] = v;
    }
    return;
  }

  // ---------------- proj role (MFMA, round-20 proven) ----------------
  unsigned* wt = (unsigned*)smem;       // 64 rows x 16 uint4 bf16x2, swizzled

  const int nodeBase = (blockIdx.x - nSort) * 64;

  // stage W -> bf16 LDS (identical layout + swizzle to round-15)
#pragma unroll
  for (int it = 0; it < 4; ++it) {
    int fi = (it * 256 + tid) * 8;        // flat float idx (8192 total)
    int row = fi >> 7, k = fi & 127;
    float4 w0 = *(const float4*)(W + fi);
    float4 w1 = *(const float4*)(W + fi + 4);
    uint4 pv;
    pv.x = pack_bf2(w0.x, w0.y);
    pv.y = pack_bf2(w0.z, w0.w);
    pv.z = pack_bf2(w1.x, w1.y);
    pv.w = pack_bf2(w1.z, w1.w);
    int c = (k >> 3) ^ ((row >> 2) & 7);  // 16B-chunk swizzle
    ((uint4*)wt)[row * 16 + c] = pv;
  }
  __syncthreads();

  const int lane = tid & 63;
  const int wid4 = tid >> 6;            // wave 0..3: H rows [16*wid4, +16)
  const int r16  = lane & 15;           // A row in stripe / B+D col in tile
  const int q    = lane >> 4;           // k-subgroup (8 bf16 each)

  const int arow = nodeBase + 16 * wid4 + r16;
  const size_t xoff = (size_t)((arow < n) ? arow : (n - 1)) * IND;

  // issue all 8 x-loads up front (independent; hide HBM latency)
  float4 xv[8];
#pragma unroll
  for (int ks = 0; ks < 4; ++ks) {
    xv[2 * ks]     = *(const float4*)(x + xoff + 32 * ks + 8 * q);
    xv[2 * ks + 1] = *(const float4*)(x + xoff + 32 * ks + 8 * q + 4);
  }

  f32x4 acc0 = {0.f, 0.f, 0.f, 0.f};
  f32x4 acc1 = {0.f, 0.f, 0.f, 0.f};
  f32x4 acc2 = {0.f, 0.f, 0.f, 0.f};
  f32x4 acc3 = {0.f, 0.f, 0.f, 0.f};

#pragma unroll
  for (int ks = 0; ks < 4; ++ks) {      // K-step: k0 = 32*ks
    float4 xa = xv[2 * ks], xb = xv[2 * ks + 1];
    bf16x8 afrag = mk_bf16x8(pack_bf2(xa.x, xa.y), pack_bf2(xa.z, xa.w),
                             pack_bf2(xb.x, xb.y), pack_bf2(xb.z, xb.w));
    // B chunk index = (k0>>3)+q = 4*ks+q, XOR row-swizzled
    {
      int row = r16;                    // col-tile 0
      uint4 bw = ((const uint4*)wt)[row * 16 + ((4 * ks + q) ^ ((row >> 2) & 7))];
      acc0 = __builtin_amdgcn_mfma_f32_16x16x32_bf16(afrag, mk_bf16x8_u4(bw), acc0, 0, 0, 0);
    }
    {
      int row = 16 + r16;               // col-tile 1
      uint4 bw = ((const uint4*)wt)[row * 16 + ((4 * ks + q) ^ ((row >> 2) & 7))];
      acc1 = __builtin_amdgcn_mfma_f32_16x16x32_bf16(afrag, mk_bf16x8_u4(bw), acc1, 0, 0, 0);
    }
    {
      int row = 32 + r16;               // col-tile 2
      uint4 bw = ((const uint4*)wt)[row * 16 + ((4 * ks + q) ^ ((row >> 2) & 7))];
      acc2 = __builtin_amdgcn_mfma_f32_16x16x32_bf16(afrag, mk_bf16x8_u4(bw), acc2, 0, 0, 0);
    }
    {
      int row = 48 + r16;               // col-tile 3
      uint4 bw = ((const uint4*)wt)[row * 16 + ((4 * ks + q) ^ ((row >> 2) & 7))];
      acc3 = __builtin_amdgcn_mfma_f32_16x16x32_bf16(afrag, mk_bf16x8_u4(bw), acc3, 0, 0, 0);
    }
  }

  // epilogue: D row = 4*q + reg (within stripe), col = t*16 + r16
  const float as0 = att_s[r16],      ad0 = att_d[r16];
  const float as1 = att_s[16 + r16], ad1 = att_d[16 + r16];
  const float as2 = att_s[32 + r16], ad2 = att_d[32 + r16];
  const float as3 = att_s[48 + r16], ad3 = att_d[48 + r16];

#pragma unroll
  for (int reg = 0; reg < 4; ++reg) {
    const int node = nodeBase + 16 * wid4 + 4 * q + reg;
    const bool ok = (node < n);
    if (ok) {
      const size_t hb = (size_t)node * HID;
      h[hb + r16]      = f2bf_bits(acc0[reg]);
      h[hb + 16 + r16] = f2bf_bits(acc1[reg]);
      h[hb + 32 + r16] = f2bf_bits(acc2[reg]);
      h[hb + 48 + r16] = f2bf_bits(acc3[reg]);
    }
    float ps = acc0[reg] * as0 + acc1[reg] * as1 + acc2[reg] * as2 + acc3[reg] * as3;
    float pd = acc0[reg] * ad0 + acc1[reg] * ad1 + acc2[reg] * ad2 + acc3[reg] * ad3;
    ps += __shfl_xor(ps, 1, 64); ps += __shfl_xor(ps, 2, 64);
    ps += __shfl_xor(ps, 4, 64); ps += __shfl_xor(ps, 8, 64);
    pd += __shfl_xor(pd, 1, 64); pd += __shfl_xor(pd, 2, 64);
    pd += __shfl_xor(pd, 4, 64); pd += __shfl_xor(pd, 8, 64);
    if (ok && r16 == 0) { a_src[node] = ps; a_dst[node] = pd; }
  }
}

// ---------------------------------------------------------------------------
// K2 (round-22): quarter-bucket CSR build (round-19 proven, unchanged) +
// NEW 4-slot gather. Gather accounting of the old wave-per-node body:
// per edge ~1 ds_bpermute (__shfl IS an LDS-port op on CDNA) + 1 VMEM
// instr (128 B / 16 lanes); per node ~18 more LDS-port shfls (acc/wsum/z
// reduces). 4-slot form: wave = 4 concurrent nodes x 16-lane slots.
//   - weight fetch = same-address LDS broadcast per slot (no shfl)
//   - acc reduction GONE (each lane owns its 4 dims end-to-end);
//     wsum identical in all 16 lanes (free); z-reduce = 4 shfls shared
//     by all 4 slots in the same instructions
//   - h-loads: 512 B per VMEM instr (4 edges) vs 128 B (1 edge) -> 4x
//     fewer VMEM issues, 4 independent load chains (MLP)
//   - cost: loop bound = max deg over 4 slots (~+25% predicated iters,
//     dummy reads hit the hot h[0] line)
// LDS-port ops/edge ~2.1 -> ~1.3; VMEM instrs/edge 1 -> 0.25.
// ---------------------------------------------------------------------------
__global__ __launch_bounds__(GT) void k_csr_gather(
    const unsigned* __restrict__ tmp, const int* __restrict__ gcur,
    const float* __restrict__ a_src, const float* __restrict__ a_dst,
    const unsigned short* __restrict__ h,
    const float* __restrict__ bias, const float* __restrict__ W_lin,
    const float* __restrict__ b_lin, float* __restrict__ y, int n)
{
  __shared__ int degl[64], sums[64], cur[64];
  __shared__ float adl[64];
  __shared__ unsigned csrw[QCAP];          // quarter CSR: (src | w_fp16<<16)

  const int tid  = threadIdx.x;
  const int blk  = blockIdx.x;
  const int b    = blk >> 2;               // coarse bucket
  const int n0   = (b << CBSHIFT) + ((blk & 3) << 6);  // first node of quarter
  const int base = b * BCAP;
  const int next = base + gcur[b];

  if (tid < 64) {
    degl[tid] = 0;
    const int node = n0 + tid;
    adl[tid] = (node < n) ? a_dst[node] : 0.f;
  }
  __syncthreads();

  // single global scan of the bucket run, cached in registers
  unsigned pkv[GSCAN];
#pragma unroll
  for (int j = 0; j < GSCAN; ++j) {
    int i = base + j * GT + tid;
    unsigned v = 0xFFFFFFFFu;
    if (i < next) {
      v = tmp[i];
      unsigned dl = (v >> 16) - (unsigned)n0;
      if (dl < 64u) atomicAdd(&degl[dl], 1);
      else v = 0xFFFFFFFFu;                // not ours: drop now
    }
    pkv[j] = v;
  }
  __syncthreads();

  if (tid < 64) sums[tid] = degl[tid];
  __syncthreads();
  for (int off = 1; off < 64; off <<= 1) {
    int t = (tid >= off && tid < 64) ? sums[tid - off] : 0;
    __syncthreads();
    if (tid < 64) sums[tid] += t;
    __syncthreads();
  }
  if (tid < 64) cur[tid] = sums[tid] - degl[tid];   // quarter-local row start
  __syncthreads();

#pragma unroll
  for (int j = 0; j < GSCAN; ++j) {
    unsigned v = pkv[j];
    if (v != 0xFFFFFFFFu) {
      unsigned dl = (v >> 16) - (unsigned)n0;
      int s = (int)(v & 0xFFFFu);
      float sc = a_src[s] + adl[dl];
      sc = (sc >= 0.f) ? sc : NEG_SLOPE * sc;
      float w = expf(sc);
      int pos = atomicAdd(&cur[dl], 1);
      if (pos < QCAP)                       // overflow guard (never fires)
        csrw[pos] = (unsigned)s | ((unsigned)f2h_bits(w) << 16);
    }
  }
  __syncthreads();

  // -------- 4-slot gather + epilogue --------
  const int lane = tid & 63;
  const int wid  = tid >> 6;               // 8 waves
  const int slot = lane >> 4;              // 4 node-slots per wave
  const int sub  = lane & 15;              // dim quad: dims 4sub .. 4sub+3

  const float4 bb4 = ((const float4*)bias)[sub];
  const float4 ww  = ((const float4*)W_lin)[sub];
  const float bl0  = b_lin[0];

#pragma unroll
  for (int half = 0; half < 2; ++half) {
    const int nl   = half * 32 + wid * 4 + slot;
    const int node = n0 + nl;
    const bool ok  = (node < n);

    int dg  = ok ? degl[nl] : 0;
    int rsl = ok ? (sums[nl] - dg) : 0;
    if (rsl >= QCAP) { rsl = 0; dg = 0; }                       // guard pair
    if (rsl + dg > QCAP) dg = (QCAP > rsl) ? (QCAP - rsl) : 0;

    // wave-uniform loop bound: max deg over the 4 slots (lane bits 4,5)
    int dgm = dg;
    dgm = max(dgm, __shfl_xor(dgm, 16, 64));
    dgm = max(dgm, __shfl_xor(dgm, 32, 64));

    float wsum = 0.f;
    float acc0 = 0.f, acc1 = 0.f, acc2 = 0.f, acc3 = 0.f;

    for (int i = 0; i < dgm; ++i) {
      const bool v = (i < dg);
      unsigned pe = csrw[v ? (rsl + i) : 0];   // broadcast within slot
      float we = v ? h2f_bits((unsigned short)(pe >> 16)) : 0.f;
      unsigned se = v ? (pe & 0xFFFFu) : 0u;
      ushort4 hb = ((const ushort4*)(h + (size_t)se * HID))[sub];
      acc0 = fmaf(we, bf2f_bits(hb.x), acc0);
      acc1 = fmaf(we, bf2f_bits(hb.y), acc1);
      acc2 = fmaf(we, bf2f_bits(hb.z), acc2);
      acc3 = fmaf(we, bf2f_bits(hb.w), acc3);
      wsum += we;
    }

    // no cross-lane acc/wsum reduction needed: each lane owns its 4 dims,
    // wsum identical in all 16 lanes of the slot.
    const float inv = 1.f / wsum;            // dg>=1 for valid nodes (self-loop)
    float v0 = fmaxf(acc0 * inv + bb4.x, 0.f);
    float v1 = fmaxf(acc1 * inv + bb4.y, 0.f);
    float v2 = fmaxf(acc2 * inv + bb4.z, 0.f);
    float v3 = fmaxf(acc3 * inv + bb4.w, 0.f);
    float z = v0 * ww.x + v1 * ww.y + v2 * ww.z + v3 * ww.w;
    z += __shfl_xor(z, 1, 64); z += __shfl_xor(z, 2, 64);
    z += __shfl_xor(z, 4, 64); z += __shfl_xor(z, 8, 64);
    if (ok && sub == 0)
      y[node] = 1.f / (1.f + expf(-(z + bl0)));
  }
}

// ---------------------------------------------------------------------------

extern "C" void kernel_launch(void* const* d_in, const int* in_sizes, int n_in,
                              void* d_out, int out_size, void* d_ws, size_t ws_size,
                              hipStream_t stream)
{
  const float* x     = (const float*)d_in[0];
  const int*   ei    = (const int*)d_in[1];
  const float* W     = (const float*)d_in[2];
  const float* att_s = (const float*)d_in[3];
  const float* att_d = (const float*)d_in[4];
  const float* bias  = (const float*)d_in[5];
  const float* W_lin = (const float*)d_in[6];
  const float* b_lin = (const float*)d_in[7];
  float* y = (float*)d_out;

  const int n = in_sizes[0] / IND;
  const int E = in_sizes[1] / 2;
  const long long E2 = (long long)E + n;
  const int nSort = (int)((E2 + EPB - 1) / EPB);         // sort blocks (208)
  const int nProj = (n + 63) / 64;                       // proj blocks (782)
  const int nbuck = (n + (1 << CBSHIFT) - 1) >> CBSHIFT; // coarse buckets (196)

  // Workspace (~13 MB). gcur zeroed by the async memset below; everything
  // else fully written before read, every call.
  char* ws = (char*)d_ws;
  unsigned short* h = (unsigned short*)ws; ws += (size_t)n * HID * sizeof(unsigned short);
  float*    a_src  = (float*)ws;    ws += (size_t)n * sizeof(float);
  float*    a_dst  = (float*)ws;    ws += (size_t)n * sizeof(float);
  int*      gcur   = (int*)ws;      ws += (size_t)nbuck * sizeof(int);
  unsigned* tmp    = (unsigned*)ws; ws += (size_t)nbuck * BCAP * sizeof(unsigned);

  hipMemsetAsync(gcur, 0, (size_t)nbuck * sizeof(int), stream);

  k_proj_sort<<<nSort + nProj, 256, 0, stream>>>(
      x, W, att_s, att_d, h, a_src, a_dst,
      ei, gcur, tmp, E, E2, nSort, nbuck, n);

  k_csr_gather<<<nbuck * 4, GT, 0, stream>>>(
      tmp, gcur, a_src, a_dst, h, bias, W_lin, b_lin, y, n);
}

// Round 9
// 119.523 us; speedup vs baseline: 1.1735x; 1.0266x over previous
//
#include <hip/hip_runtime.h>
#include <hip/hip_bf16.h>
#include <hip/hip_fp16.h>
#include <cstdint>

#define IND 128
#define HID 64
#define NEG_SLOPE 0.2f
#define EPB 4096      // edges per sort block
#define CBSHIFT 8     // coarse bucket = 256 consecutive dst nodes
#define BCAP 8192     // fixed bucket capacity (mean 4352, +60 sigma headroom)
#define SORT_THREADS 256
#define EPT (EPB / SORT_THREADS)   // 16 edges per thread in sort role
#define QCAP 2048     // quarter-bucket CSR capacity (mean 1088, +29 sigma)
#define GT 512        // gather-block threads

typedef __attribute__((ext_vector_type(8))) short bf16x8;
typedef __attribute__((ext_vector_type(4))) float f32x4;

__device__ __forceinline__ unsigned short f2bf_bits(float f) {
  __hip_bfloat16 b = __float2bfloat16(f);
  return *reinterpret_cast<unsigned short*>(&b);
}
__device__ __forceinline__ unsigned short f2h_bits(float f) {
  __half h = __float2half(f);
  return *reinterpret_cast<unsigned short*>(&h);
}
__device__ __forceinline__ float h2f_bits(unsigned short u) {
  __half_raw r; r.x = u;
  return __half2float(__half(r));
}
__device__ __forceinline__ float bf2f_bits(unsigned short u) {
  return __uint_as_float((unsigned)u << 16);
}
__device__ __forceinline__ float bf_lo(unsigned u) {
  return __uint_as_float(u << 16);
}
__device__ __forceinline__ float bf_hi(unsigned u) {
  return __uint_as_float(u & 0xFFFF0000u);
}
__device__ __forceinline__ unsigned pack_bf2(float lo, float hi) {
  return (unsigned)f2bf_bits(lo) | ((unsigned)f2bf_bits(hi) << 16);
}
__device__ __forceinline__ bf16x8 mk_bf16x8(unsigned a, unsigned b,
                                            unsigned c, unsigned d) {
  union { unsigned u[4]; bf16x8 v; } t;
  t.u[0] = a; t.u[1] = b; t.u[2] = c; t.u[3] = d;
  return t.v;
}
__device__ __forceinline__ bf16x8 mk_bf16x8_u4(uint4 u) {
  union { uint4 u4; bf16x8 v; } t;
  t.u4 = u;
  return t.v;
}

// ---------------------------------------------------------------------------
// K1 (fused): proj + sortout in one grid, block-role split.
//   blocks [0, nSort)        : counting-sort role (round-16 proven, 256 bkts)
//   blocks [nSort, nSort+nP) : projection role — MFMA (round-20 proven)
// Unchanged from round 8 (122.7 us best). gcur zeroed by hipMemsetAsync.
// ---------------------------------------------------------------------------
__global__ __launch_bounds__(256) void k_proj_sort(
    const float* __restrict__ x, const float* __restrict__ W,
    const float* __restrict__ att_s, const float* __restrict__ att_d,
    unsigned short* __restrict__ h, float* __restrict__ a_src,
    float* __restrict__ a_dst,
    const int* __restrict__ ei, int* __restrict__ gcur,
    unsigned* __restrict__ tmp, int E, long long E2,
    int nSort, int nbuck, int n)
{
  __shared__ __align__(16) char smem[20480];
  const int tid = threadIdx.x;

  if (blockIdx.x < (unsigned)nSort) {
    // ---------------- sort role ----------------
    int* hist       = (int*)smem;            // 256 ints: counts, then lstart
    int* sums       = hist + 256;
    int* cur        = sums + 256;
    int* gbase      = cur + 256;             // reserved global run base
    unsigned* sorted = (unsigned*)(gbase + 256);   // EPB entries (16 KB)

    hist[tid] = 0;
    __syncthreads();

    const long long i0 = (long long)blockIdx.x * EPB;

    unsigned pk[EPT];
#pragma unroll
    for (int j = 0; j < EPT; ++j) {
      long long idx = i0 + j * SORT_THREADS + tid;
      unsigned v = 0xFFFFFFFFu;
      if (idx < E2) {
        int s, d;
        if (idx < E) { s = ei[idx]; d = ei[E + idx]; }
        else         { s = d = (int)(idx - E); }
        v = ((unsigned)d << 16) | (unsigned)s;
        atomicAdd(&hist[d >> CBSHIFT], 1);
      }
      pk[j] = v;
    }
    __syncthreads();

    sums[tid] = hist[tid];
    __syncthreads();
    for (int off = 1; off < 256; off <<= 1) {
      int t = (tid >= off) ? sums[tid - off] : 0;
      __syncthreads();
      sums[tid] += t;
      __syncthreads();
    }
    {
      const int lstart_t = sums[tid] - hist[tid];
      cur[tid] = lstart_t;
      gbase[tid] = (tid < nbuck && hist[tid] > 0)
                     ? tid * BCAP + atomicAdd(&gcur[tid], hist[tid]) : 0;
    }
    __syncthreads();
    hist[tid] = sums[tid] - hist[tid];   // hist := lstart
    __syncthreads();

#pragma unroll
    for (int j = 0; j < EPT; ++j) {
      unsigned v = pk[j];
      if (v != 0xFFFFFFFFu) {
        int b = v >> (16 + CBSHIFT);
        int lpos = atomicAdd(&cur[b], 1);
        sorted[lpos] = v;
      }
    }
    __syncthreads();

    const int cntE = (int)((E2 - i0 < EPB) ? (E2 - i0) : EPB);
    for (int i = tid; i < cntE; i += SORT_THREADS) {
      unsigned v = sorted[i];
      int b = v >> (16 + CBSHIFT);
      tmp[gbase[b] + (i - hist[b])] = v;
    }
    return;
  }

  // ---------------- proj role (MFMA, round-20 proven) ----------------
  unsigned* wt = (unsigned*)smem;       // 64 rows x 16 uint4 bf16x2, swizzled

  const int nodeBase = (blockIdx.x - nSort) * 64;

  // stage W -> bf16 LDS (identical layout + swizzle to round-15)
#pragma unroll
  for (int it = 0; it < 4; ++it) {
    int fi = (it * 256 + tid) * 8;        // flat float idx (8192 total)
    int row = fi >> 7, k = fi & 127;
    float4 w0 = *(const float4*)(W + fi);
    float4 w1 = *(const float4*)(W + fi + 4);
    uint4 pv;
    pv.x = pack_bf2(w0.x, w0.y);
    pv.y = pack_bf2(w0.z, w0.w);
    pv.z = pack_bf2(w1.x, w1.y);
    pv.w = pack_bf2(w1.z, w1.w);
    int c = (k >> 3) ^ ((row >> 2) & 7);  // 16B-chunk swizzle
    ((uint4*)wt)[row * 16 + c] = pv;
  }
  __syncthreads();

  const int lane = tid & 63;
  const int wid4 = tid >> 6;            // wave 0..3: H rows [16*wid4, +16)
  const int r16  = lane & 15;           // A row in stripe / B+D col in tile
  const int q    = lane >> 4;           // k-subgroup (8 bf16 each)

  const int arow = nodeBase + 16 * wid4 + r16;
  const size_t xoff = (size_t)((arow < n) ? arow : (n - 1)) * IND;

  // issue all 8 x-loads up front (independent; hide HBM latency)
  float4 xv[8];
#pragma unroll
  for (int ks = 0; ks < 4; ++ks) {
    xv[2 * ks]     = *(const float4*)(x + xoff + 32 * ks + 8 * q);
    xv[2 * ks + 1] = *(const float4*)(x + xoff + 32 * ks + 8 * q + 4);
  }

  f32x4 acc0 = {0.f, 0.f, 0.f, 0.f};
  f32x4 acc1 = {0.f, 0.f, 0.f, 0.f};
  f32x4 acc2 = {0.f, 0.f, 0.f, 0.f};
  f32x4 acc3 = {0.f, 0.f, 0.f, 0.f};

#pragma unroll
  for (int ks = 0; ks < 4; ++ks) {      // K-step: k0 = 32*ks
    float4 xa = xv[2 * ks], xb = xv[2 * ks + 1];
    bf16x8 afrag = mk_bf16x8(pack_bf2(xa.x, xa.y), pack_bf2(xa.z, xa.w),
                             pack_bf2(xb.x, xb.y), pack_bf2(xb.z, xb.w));
    // B chunk index = (k0>>3)+q = 4*ks+q, XOR row-swizzled
    {
      int row = r16;                    // col-tile 0
      uint4 bw = ((const uint4*)wt)[row * 16 + ((4 * ks + q) ^ ((row >> 2) & 7))];
      acc0 = __builtin_amdgcn_mfma_f32_16x16x32_bf16(afrag, mk_bf16x8_u4(bw), acc0, 0, 0, 0);
    }
    {
      int row = 16 + r16;               // col-tile 1
      uint4 bw = ((const uint4*)wt)[row * 16 + ((4 * ks + q) ^ ((row >> 2) & 7))];
      acc1 = __builtin_amdgcn_mfma_f32_16x16x32_bf16(afrag, mk_bf16x8_u4(bw), acc1, 0, 0, 0);
    }
    {
      int row = 32 + r16;               // col-tile 2
      uint4 bw = ((const uint4*)wt)[row * 16 + ((4 * ks + q) ^ ((row >> 2) & 7))];
      acc2 = __builtin_amdgcn_mfma_f32_16x16x32_bf16(afrag, mk_bf16x8_u4(bw), acc2, 0, 0, 0);
    }
    {
      int row = 48 + r16;               // col-tile 3
      uint4 bw = ((const uint4*)wt)[row * 16 + ((4 * ks + q) ^ ((row >> 2) & 7))];
      acc3 = __builtin_amdgcn_mfma_f32_16x16x32_bf16(afrag, mk_bf16x8_u4(bw), acc3, 0, 0, 0);
    }
  }

  // epilogue: D row = 4*q + reg (within stripe), col = t*16 + r16
  const float as0 = att_s[r16],      ad0 = att_d[r16];
  const float as1 = att_s[16 + r16], ad1 = att_d[16 + r16];
  const float as2 = att_s[32 + r16], ad2 = att_d[32 + r16];
  const float as3 = att_s[48 + r16], ad3 = att_d[48 + r16];

#pragma unroll
  for (int reg = 0; reg < 4; ++reg) {
    const int node = nodeBase + 16 * wid4 + 4 * q + reg;
    const bool ok = (node < n);
    if (ok) {
      const size_t hb = (size_t)node * HID;
      h[hb + r16]      = f2bf_bits(acc0[reg]);
      h[hb + 16 + r16] = f2bf_bits(acc1[reg]);
      h[hb + 32 + r16] = f2bf_bits(acc2[reg]);
      h[hb + 48 + r16] = f2bf_bits(acc3[reg]);
    }
    float ps = acc0[reg] * as0 + acc1[reg] * as1 + acc2[reg] * as2 + acc3[reg] * as3;
    float pd = acc0[reg] * ad0 + acc1[reg] * ad1 + acc2[reg] * ad2 + acc3[reg] * ad3;
    ps += __shfl_xor(ps, 1, 64); ps += __shfl_xor(ps, 2, 64);
    ps += __shfl_xor(ps, 4, 64); ps += __shfl_xor(ps, 8, 64);
    pd += __shfl_xor(pd, 1, 64); pd += __shfl_xor(pd, 2, 64);
    pd += __shfl_xor(pd, 4, 64); pd += __shfl_xor(pd, 8, 64);
    if (ok && r16 == 0) { a_src[node] = ps; a_dst[node] = pd; }
  }
}

// ---------------------------------------------------------------------------
// K2 (round-23): quarter-bucket CSR build + 8-SLOT gather.
// Changes vs round-22 (both instruction-count cuts, same arithmetic):
//  (1) scan reads tmp as uint4: 4 entries/thread/instr -> scan VMEM
//      instrs 16 -> 4 per thread (same bytes, same histogram).
//  (2) gather: slot = 8 lanes x 8 dims, h row read as uint4 (16 B/lane,
//      coalescing sweet spot). VMEM instrs/edge 0.25 -> ~0.125(1+idle);
//      all 64 nodes in ONE pass (halves loop gone -> half the loop
//      overhead + epilogue); z-reduce 4 -> 3 shfls. Cost: loop bound =
//      max deg over 8 slots (E[max8]~22.6 vs E[max4]~20.9, ~+6% idle;
//      dummy reads hit the hot h[0] line).
// ---------------------------------------------------------------------------
__device__ __forceinline__ unsigned csr_scan_one(
    unsigned v, int ge, int run, unsigned n0, int* degl)
{
  if (ge < run) {
    unsigned dl = (v >> 16) - n0;
    if (dl < 64u) { atomicAdd(&degl[dl], 1); return v; }
  }
  return 0xFFFFFFFFu;
}

__global__ __launch_bounds__(GT) void k_csr_gather(
    const unsigned* __restrict__ tmp, const int* __restrict__ gcur,
    const float* __restrict__ a_src, const float* __restrict__ a_dst,
    const unsigned short* __restrict__ h,
    const float* __restrict__ bias, const float* __restrict__ W_lin,
    const float* __restrict__ b_lin, float* __restrict__ y, int n)
{
  __shared__ int degl[64], sums[64], cur[64];
  __shared__ float adl[64];
  __shared__ unsigned csrw[QCAP];          // quarter CSR: (src | w_fp16<<16)

  const int tid  = threadIdx.x;
  const int blk  = blockIdx.x;
  const int b    = blk >> 2;               // coarse bucket
  const int n0   = (b << CBSHIFT) + ((blk & 3) << 6);  // first node of quarter
  const int base = b * BCAP;
  const int run  = gcur[b];

  if (tid < 64) {
    degl[tid] = 0;
    const int node = n0 + tid;
    adl[tid] = (node < n) ? a_dst[node] : 0.f;
  }
  __syncthreads();

  // vectorized scan of the bucket run (uint4 = 4 entries), reg-cached
  const uint4* tmp4 = (const uint4*)(tmp + base);
  unsigned pkv[16];
#pragma unroll
  for (int j = 0; j < 4; ++j) {
    uint4 v4 = tmp4[j * GT + tid];
    int ge = (j * GT + tid) * 4;
    pkv[4 * j + 0] = csr_scan_one(v4.x, ge + 0, run, (unsigned)n0, degl);
    pkv[4 * j + 1] = csr_scan_one(v4.y, ge + 1, run, (unsigned)n0, degl);
    pkv[4 * j + 2] = csr_scan_one(v4.z, ge + 2, run, (unsigned)n0, degl);
    pkv[4 * j + 3] = csr_scan_one(v4.w, ge + 3, run, (unsigned)n0, degl);
  }
  __syncthreads();

  if (tid < 64) sums[tid] = degl[tid];
  __syncthreads();
  for (int off = 1; off < 64; off <<= 1) {
    int t = (tid >= off && tid < 64) ? sums[tid - off] : 0;
    __syncthreads();
    if (tid < 64) sums[tid] += t;
    __syncthreads();
  }
  if (tid < 64) cur[tid] = sums[tid] - degl[tid];   // quarter-local row start
  __syncthreads();

#pragma unroll
  for (int j = 0; j < 16; ++j) {
    unsigned v = pkv[j];
    if (v != 0xFFFFFFFFu) {
      unsigned dl = (v >> 16) - (unsigned)n0;
      int s = (int)(v & 0xFFFFu);
      float sc = a_src[s] + adl[dl];
      sc = (sc >= 0.f) ? sc : NEG_SLOPE * sc;
      float w = expf(sc);
      int pos = atomicAdd(&cur[dl], 1);
      if (pos < QCAP)                       // overflow guard (never fires)
        csrw[pos] = (unsigned)s | ((unsigned)f2h_bits(w) << 16);
    }
  }
  __syncthreads();

  // -------- 8-slot gather + epilogue (one pass covers all 64 nodes) ------
  const int lane = tid & 63;
  const int wid  = tid >> 6;               // 8 waves
  const int slot = lane >> 3;              // 8 node-slots per wave
  const int sub  = lane & 7;               // dim octet: dims 8sub .. 8sub+7

  const int nl   = wid * 8 + slot;         // 8 waves x 8 slots = 64 nodes
  const int node = n0 + nl;
  const bool ok  = (node < n);

  int dg  = ok ? degl[nl] : 0;
  int rsl = ok ? (sums[nl] - dg) : 0;
  if (rsl >= QCAP) { rsl = 0; dg = 0; }                       // guard pair
  if (rsl + dg > QCAP) dg = (QCAP > rsl) ? (QCAP - rsl) : 0;

  // wave-uniform loop bound: max deg over the 8 slots (lane bits 3,4,5)
  int dgm = dg;
  dgm = max(dgm, __shfl_xor(dgm, 8, 64));
  dgm = max(dgm, __shfl_xor(dgm, 16, 64));
  dgm = max(dgm, __shfl_xor(dgm, 32, 64));

  float wsum = 0.f;
  float a0 = 0.f, a1 = 0.f, a2 = 0.f, a3 = 0.f;
  float a4 = 0.f, a5 = 0.f, a6 = 0.f, a7 = 0.f;

  for (int i = 0; i < dgm; ++i) {
    const bool v = (i < dg);
    unsigned pe = csrw[v ? (rsl + i) : 0];     // broadcast within slot
    float we = v ? h2f_bits((unsigned short)(pe >> 16)) : 0.f;
    unsigned se = v ? (pe & 0xFFFFu) : 0u;
    uint4 hb = ((const uint4*)(h + (size_t)se * HID))[sub];  // 8 bf16 dims
    a0 = fmaf(we, bf_lo(hb.x), a0);
    a1 = fmaf(we, bf_hi(hb.x), a1);
    a2 = fmaf(we, bf_lo(hb.y), a2);
    a3 = fmaf(we, bf_hi(hb.y), a3);
    a4 = fmaf(we, bf_lo(hb.z), a4);
    a5 = fmaf(we, bf_hi(hb.z), a5);
    a6 = fmaf(we, bf_lo(hb.w), a6);
    a7 = fmaf(we, bf_hi(hb.w), a7);
    wsum += we;
  }

  // each lane owns dims 8sub..8sub+7 end-to-end; wsum identical within slot
  const float inv = 1.f / wsum;              // dg>=1 for valid nodes (self-loop)
  const float4 bbA = ((const float4*)bias)[2 * sub];
  const float4 bbB = ((const float4*)bias)[2 * sub + 1];
  const float4 wwA = ((const float4*)W_lin)[2 * sub];
  const float4 wwB = ((const float4*)W_lin)[2 * sub + 1];
  float v0 = fmaxf(a0 * inv + bbA.x, 0.f);
  float v1 = fmaxf(a1 * inv + bbA.y, 0.f);
  float v2 = fmaxf(a2 * inv + bbA.z, 0.f);
  float v3 = fmaxf(a3 * inv + bbA.w, 0.f);
  float v4 = fmaxf(a4 * inv + bbB.x, 0.f);
  float v5 = fmaxf(a5 * inv + bbB.y, 0.f);
  float v6 = fmaxf(a6 * inv + bbB.z, 0.f);
  float v7 = fmaxf(a7 * inv + bbB.w, 0.f);
  float z = v0 * wwA.x + v1 * wwA.y + v2 * wwA.z + v3 * wwA.w
          + v4 * wwB.x + v5 * wwB.y + v6 * wwB.z + v7 * wwB.w;
  z += __shfl_xor(z, 1, 64); z += __shfl_xor(z, 2, 64);
  z += __shfl_xor(z, 4, 64);
  if (ok && sub == 0)
    y[node] = 1.f / (1.f + expf(-(z + b_lin[0])));
}

// ---------------------------------------------------------------------------

extern "C" void kernel_launch(void* const* d_in, const int* in_sizes, int n_in,
                              void* d_out, int out_size, void* d_ws, size_t ws_size,
                              hipStream_t stream)
{
  const float* x     = (const float*)d_in[0];
  const int*   ei    = (const int*)d_in[1];
  const float* W     = (const float*)d_in[2];
  const float* att_s = (const float*)d_in[3];
  const float* att_d = (const float*)d_in[4];
  const float* bias  = (const float*)d_in[5];
  const float* W_lin = (const float*)d_in[6];
  const float* b_lin = (const float*)d_in[7];
  float* y = (float*)d_out;

  const int n = in_sizes[0] / IND;
  const int E = in_sizes[1] / 2;
  const long long E2 = (long long)E + n;
  const int nSort = (int)((E2 + EPB - 1) / EPB);         // sort blocks (208)
  const int nProj = (n + 63) / 64;                       // proj blocks (782)
  const int nbuck = (n + (1 << CBSHIFT) - 1) >> CBSHIFT; // coarse buckets (196)

  // Workspace (~13 MB). gcur zeroed by the async memset below; everything
  // else fully written before read, every call.
  char* ws = (char*)d_ws;
  unsigned short* h = (unsigned short*)ws; ws += (size_t)n * HID * sizeof(unsigned short);
  float*    a_src  = (float*)ws;    ws += (size_t)n * sizeof(float);
  float*    a_dst  = (float*)ws;    ws += (size_t)n * sizeof(float);
  int*      gcur   = (int*)ws;      ws += (size_t)nbuck * sizeof(int);
  unsigned* tmp    = (unsigned*)ws; ws += (size_t)nbuck * BCAP * sizeof(unsigned);

  hipMemsetAsync(gcur, 0, (size_t)nbuck * sizeof(int), stream);

  k_proj_sort<<<nSort + nProj, 256, 0, stream>>>(
      x, W, att_s, att_d, h, a_src, a_dst,
      ei, gcur, tmp, E, E2, nSort, nbuck, n);

  k_csr_gather<<<nbuck * 4, GT, 0, stream>>>(
      tmp, gcur, a_src, a_dst, h, bias, W_lin, b_lin, y, n);
}